// Round 10
// baseline (351.019 us; speedup 1.0000x reference)
//
#include <hip/hip_runtime.h>
#include <hip/hip_bf16.h>

// Problem constants
#define BB 8
#define NN 1024
#define BN 8192       // B*N
#define DD 256
#define HEADS 4
#define HD 1024       // HEADS*D
#define DSS 768
#define DTT 128
#define NE 131072     // raw edges
#define NEP (NE + BN) // + self loops
#define DEGCAP 256    // LDS-cached edges per node (max in-degree ~40 for this input)

typedef __hip_bfloat16 bf16;
typedef __attribute__((ext_vector_type(8))) short short8;   // 8 bf16 (4 VGPRs)
typedef __attribute__((ext_vector_type(4))) float floatx4;  // MFMA C/D

__device__ __forceinline__ float toF(bf16 x){ return __bfloat162float(x); }
__device__ __forceinline__ void stC(float* p, float v){ *p = v; }
__device__ __forceinline__ void stC(bf16* p, float v){ *p = __float2bfloat16(v); }
__device__ __forceinline__ float bf_lo(unsigned u){ return __uint_as_float(u << 16); }
__device__ __forceinline__ float bf_hi(unsigned u){ return __uint_as_float(u & 0xffff0000u); }

// load 8 contiguous elements as 8 bf16 (uint4) — native or convert-on-load
__device__ __forceinline__ uint4 ld8bf(const bf16* p){ return *(const uint4*)p; }
__device__ __forceinline__ uint4 ld8bf(const float* p){
  float4 v0 = *(const float4*)p;
  float4 v1 = *(const float4*)(p + 4);
  bf16 t[8] = {__float2bfloat16(v0.x), __float2bfloat16(v0.y),
               __float2bfloat16(v0.z), __float2bfloat16(v0.w),
               __float2bfloat16(v1.x), __float2bfloat16(v1.y),
               __float2bfloat16(v1.z), __float2bfloat16(v1.w)};
  return *(uint4*)t;
}

__device__ __forceinline__ float wredsum(float v){
  #pragma unroll
  for (int off = 32; off; off >>= 1) v += __shfl_xor(v, off);
  return v;
}
__device__ __forceinline__ float wredmax(float v){
  #pragma unroll
  for (int off = 32; off; off >>= 1) v = fmaxf(v, __shfl_xor(v, off));
  return v;
}

// transpose one 32x32 tile: dst[c][r] = bf16(src[r][c]) (whole block same branch)
__device__ __forceinline__ void dev_transpose(
    float tb[32][33], const float* __restrict__ src, bf16* __restrict__ dst,
    int R, int C, int bx, int by, int tid)
{
  int c0 = bx*32, r0 = by*32;
  int tr = tid >> 5, tc = tid & 31;
  #pragma unroll
  for (int i = 0; i < 4; i++)
    tb[tr + i*8][tc] = src[(size_t)(r0 + tr + i*8)*C + c0 + tc];
  __syncthreads();
  #pragma unroll
  for (int i = 0; i < 4; i++)
    dst[(size_t)(c0 + tr + i*8)*R + r0 + tc] = __float2bfloat16(tb[tc][tr + i*8]);
}

// ---------------------------------------------------------------------------
// prep1: independent prep work, partitioned by block range (928 blocks).
//  [0,32) textf/editp  [32,128) WfullT  [128,384) g1T  [384,640) g2T
//  [640,704) cw1T  [704,768) aw1T  [768,896) WdT+bias23  [896,928) CSR init
// ---------------------------------------------------------------------------
__global__ __launch_bounds__(256) void prep1(
    const float* __restrict__ text_emb, const float* __restrict__ edit_emb,
    const float* __restrict__ wt, const float* __restrict__ bt,
    const float* __restrict__ we, const float* __restrict__ be,
    float* __restrict__ textf, float* __restrict__ editp,
    const float* __restrict__ wsm, const float* __restrict__ wp, bf16* __restrict__ WfT,
    const float* __restrict__ g1_lin, bf16* __restrict__ g1T,
    const float* __restrict__ g2_lin, bf16* __restrict__ g2T,
    const float* __restrict__ cw1, const float* __restrict__ aw1, bf16* __restrict__ W2T,
    const float* __restrict__ cw2, const float* __restrict__ cb2,
    const float* __restrict__ aw2, const float* __restrict__ ab2,
    bf16* __restrict__ WdT, float* __restrict__ bias23,
    int* __restrict__ counts, int* __restrict__ fc, float* __restrict__ zz,
    const float* __restrict__ cb1, const float* __restrict__ ab1, float* __restrict__ bias2)
{
  __shared__ float tpose[32][33];
  __shared__ float red[2][4][64];
  int blk = blockIdx.x, tid = threadIdx.x;
  if (blk < 32) {
    int b = blk & 7, l = tid & 63, qq = tid >> 6;
    int d = (blk >> 3)*64 + l;
    float tf = 0.f;
    for (int k = qq*32; k < qq*32 + 32; k++) tf += text_emb[b*DTT + k] * wt[(size_t)k*DD + d];
    float ep = 0.f;
    for (int k = qq*192; k < qq*192 + 192; k++) ep += edit_emb[b*DSS + k] * we[(size_t)k*DD + d];
    red[0][qq][l] = tf; red[1][qq][l] = ep;
    __syncthreads();
    if (tid < 64) {
      int dd = (blk >> 3)*64 + tid;
      textf[b*DD + dd] = red[0][0][tid]+red[0][1][tid]+red[0][2][tid]+red[0][3][tid] + bt[dd];
      editp[b*DD + dd] = red[1][0][tid]+red[1][1][tid]+red[1][2][tid]+red[1][3][tid] + be[dd];
    }
  } else if (blk < 128) {
    int k0 = (blk - 32)*8, d = tid;
    float acc[8] = {};
    for (int j = 0; j < DD; j++) {
      float wv = wp[(size_t)j*DD + d];
      #pragma unroll
      for (int kk = 0; kk < 8; kk++) acc[kk] += wsm[(size_t)(k0 + kk)*DD + j] * wv;
    }
    #pragma unroll
    for (int kk = 0; kk < 8; kk++) WfT[(size_t)d*DSS + k0 + kk] = __float2bfloat16(acc[kk]);
  } else if (blk < 384) {
    int lo = blk - 128; dev_transpose(tpose, g1_lin, g1T, DD, HD, lo & 31, lo >> 5, tid);
  } else if (blk < 640) {
    int lo = blk - 384; dev_transpose(tpose, g2_lin, g2T, DD, HD, lo & 31, lo >> 5, tid);
  } else if (blk < 704) {
    int lo = blk - 640; dev_transpose(tpose, cw1, W2T, DD, DD, lo & 7, lo >> 3, tid);
  } else if (blk < 768) {
    int lo = blk - 704; dev_transpose(tpose, aw1, W2T + 65536, DD, DD, lo & 7, lo >> 3, tid);
  } else if (blk < 896) {
    int idx = (blk - 768)*256 + tid;      // 0..32767
    int n = idx >> 9, k = idx & 511;
    float v = 0.f;
    if (n < 3) { if (k < 256) v = cw2[(size_t)k*3 + n]; }
    else if (n < 23) { if (k >= 256) v = aw2[(size_t)(k - 256)*20 + (n - 3)]; }
    WdT[idx] = __float2bfloat16(v);
    if (idx < 64) bias23[idx] = idx < 3 ? cb2[idx] : (idx < 23 ? ab2[idx - 3] : 0.f);
  } else {
    int i = (blk - 896)*256 + tid;        // 0..8191
    counts[i] = 1; fc[i] = 0;
    float4 z = make_float4(0.f, 0.f, 0.f, 0.f);
    #pragma unroll
    for (int j = 0; j < 4; j++) ((float4*)zz)[i*4 + j] = z;
    if (i < 256) bias2[i] = cb1[i];
    else if (i < 512) bias2[i] = ab1[i - 256];
  }
}

// ---------------------------------------------------------------------------
// prep2: vh + cvec + edge counting;  prep3: mhavec + CSR scan
// ---------------------------------------------------------------------------
__global__ __launch_bounds__(256) void prep2(
    const float* __restrict__ textf, const float* __restrict__ editp,
    const float* __restrict__ mha_iw, const float* __restrict__ mha_ib, float* __restrict__ vh,
    const float* __restrict__ bs, const float* __restrict__ wp, const float* __restrict__ bp,
    float* __restrict__ cvec,
    const int* __restrict__ ei, int* __restrict__ counts)
{
  __shared__ float red[4][64];
  int blk = blockIdx.x, tid = threadIdx.x;
  if (blk < 512) {
    int b = blk & 7, w = tid >> 6, l = tid & 63;
    int d = (blk >> 3)*4 + w;
    float p = 0.f;
    #pragma unroll
    for (int i = 0; i < 4; i++) p += textf[b*DD + l + 64*i] * mha_iw[(size_t)(512 + d)*DD + l + 64*i];
    p = wredsum(p);
    if (l == 0) vh[b*DD + d] = p + mha_ib[512 + d];
  } else if (blk < 544) {
    int lo = blk - 512;
    int b = lo & 7, l = tid & 63, qq = tid >> 6;
    int d = (lo >> 3)*64 + l;
    float cv = 0.f;
    for (int k = qq*64; k < qq*64 + 64; k++) cv += bs[k] * wp[(size_t)k*DD + d];
    for (int k = qq*64; k < qq*64 + 64; k++) cv += textf[b*DD + k] * wp[(size_t)(DD + k)*DD + d];
    for (int k = qq*64; k < qq*64 + 64; k++) cv += editp[b*DD + k] * wp[(size_t)(2*DD + k)*DD + d];
    red[qq][l] = cv;
    __syncthreads();
    if (tid < 64) {
      int dd = (lo >> 3)*64 + tid;
      cvec[b*DD + dd] = red[0][tid]+red[1][tid]+red[2][tid]+red[3][tid] + bp[dd] + editp[b*DD + dd];
    }
  } else {
    int e = (blk - 544)*256 + tid;
    if (e < NE) atomicAdd(&counts[ei[NE + e]], 1);
  }
}

__global__ __launch_bounds__(1024) void prep3(
    const float* __restrict__ vh, const float* __restrict__ mha_ow,
    const float* __restrict__ mha_ob, float* __restrict__ mhavec,
    const int* __restrict__ counts, int* __restrict__ offs)
{
  __shared__ int part[1024];
  int blk = blockIdx.x, t = threadIdx.x;
  if (blk < 128) {
    int b = blk >> 4, w16 = t >> 6, l = t & 63;
    int d = (blk & 15)*16 + w16;
    float p = 0.f;
    #pragma unroll
    for (int i = 0; i < 4; i++) p += vh[b*DD + l + 64*i] * mha_ow[(size_t)d*DD + l + 64*i];
    p = wredsum(p);
    if (l == 0) mhavec[b*DD + d] = p + mha_ob[d];
  } else {
    int local[8]; int sum = 0;
    #pragma unroll
    for (int i = 0; i < 8; i++) { local[i] = sum; sum += counts[t*8 + i]; }
    part[t] = sum;
    __syncthreads();
    for (int off = 1; off < 1024; off <<= 1) {
      int v = (t >= off) ? part[t - off] : 0;
      __syncthreads();
      part[t] += v;
      __syncthreads();
    }
    int base = (t == 0) ? 0 : part[t - 1];
    #pragma unroll
    for (int i = 0; i < 8; i++) offs[t*8 + i] = base + local[i];
    if (t == 1023) offs[BN] = part[1023];
  }
}

__global__ void csr_fill(const int* __restrict__ ei, const int* __restrict__ offs,
                         int* __restrict__ fc, int* __restrict__ csr)
{
  int idx = blockIdx.x*256 + threadIdx.x;
  if (idx < NE) {
    int sn = ei[idx], dn = ei[NE + idx];
    int p = offs[dn] + atomicAdd(&fc[dn], 1);
    csr[p] = sn;
  } else if (idx < NEP) {
    int i2 = idx - NE;
    int p = offs[i2] + atomicAdd(&fc[i2], 1);
    csr[p] = i2;
  }
}

// ---------------------------------------------------------------------------
// MFMA GEMM: C[M,N] = A[M,K] @ Bt[N,K]^T, 64x64 tile, fp32 acc.
// A may be fp32 (converted to bf16 while staging) or bf16.
// (128-tile regressed 3x in round 8: VGPR spill to scratch. Stay at 64.)
// Optional fused epilogues: bias/rowvec/relu; GAT attention-score partials.
// ---------------------------------------------------------------------------
template<typename TA, typename TC>
__global__ __launch_bounds__(256) void gemm_mfma(
    const TA* __restrict__ A, const bf16* __restrict__ Bt, TC* __restrict__ C,
    int M, int N, int K,
    const float* __restrict__ bias, const float* __restrict__ rowvec, int relu,
    const float* __restrict__ atts, const float* __restrict__ attd,
    float* __restrict__ as_out, float* __restrict__ ad_out)
{
  __shared__ __align__(16) bf16 Asl[64*72];
  __shared__ __align__(16) bf16 Bsl[64*72];
  int tid = threadIdx.x;
  int w = tid >> 6, lane = tid & 63;
  int q = lane >> 4, mn = lane & 15;
  int row0 = blockIdx.y*64, col0 = blockIdx.x*64;
  int sr = tid >> 3, sc = tid & 7;
  floatx4 acc[4];
  #pragma unroll
  for (int t = 0; t < 4; t++) acc[t] = (floatx4){0.f, 0.f, 0.f, 0.f};

  for (int k0 = 0; k0 < K; k0 += 64) {
    uint4 a0 = ld8bf(A  + (size_t)(row0 + sr)*K      + k0 + sc*8);
    uint4 a1 = ld8bf(A  + (size_t)(row0 + 32 + sr)*K + k0 + sc*8);
    uint4 b0 = ld8bf(Bt + (size_t)(col0 + sr)*K      + k0 + sc*8);
    uint4 b1 = ld8bf(Bt + (size_t)(col0 + 32 + sr)*K + k0 + sc*8);
    __syncthreads();
    *(uint4*)&Asl[sr*72 + sc*8]        = a0;
    *(uint4*)&Asl[(sr + 32)*72 + sc*8] = a1;
    *(uint4*)&Bsl[sr*72 + sc*8]        = b0;
    *(uint4*)&Bsl[(sr + 32)*72 + sc*8] = b1;
    __syncthreads();
    #pragma unroll
    for (int kk = 0; kk < 64; kk += 32) {
      short8 af = *(const short8*)&Asl[(w*16 + mn)*72 + kk + q*8];
      #pragma unroll
      for (int t = 0; t < 4; t++) {
        short8 bfr = *(const short8*)&Bsl[(t*16 + mn)*72 + kk + q*8];
        acc[t] = __builtin_amdgcn_mfma_f32_16x16x32_bf16(af, bfr, acc[t], 0, 0, 0);
      }
    }
  }
  if (as_out) {   // fused GAT attention-score partials (head h = col0>>8)
    int h = col0 >> 8, cbase = col0 & 255;
    float ps[4] = {}, pd[4] = {};
    #pragma unroll
    for (int t = 0; t < 4; t++) {
      float av = atts[h*DD + cbase + t*16 + mn];
      float dv = attd[h*DD + cbase + t*16 + mn];
      #pragma unroll
      for (int rg = 0; rg < 4; rg++) {
        ps[rg] += acc[t][rg]*av;
        pd[rg] += acc[t][rg]*dv;
      }
    }
    #pragma unroll
    for (int rg = 0; rg < 4; rg++) {
      #pragma unroll
      for (int off = 1; off < 16; off <<= 1) {
        ps[rg] += __shfl_xor(ps[rg], off);
        pd[rg] += __shfl_xor(pd[rg], off);
      }
      if (mn == 0) {
        int r = row0 + w*16 + q*4 + rg;
        atomicAdd(&as_out[r*4 + h], ps[rg]);
        atomicAdd(&ad_out[r*4 + h], pd[rg]);
      }
    }
  }
  #pragma unroll
  for (int t = 0; t < 4; t++) {
    #pragma unroll
    for (int rg = 0; rg < 4; rg++) {
      int r = row0 + w*16 + q*4 + rg;
      int c = col0 + t*16 + mn;
      float v = acc[t][rg];
      if (bias)   v += bias[c];
      if (rowvec) v += rowvec[(size_t)(r >> 10)*N + c];
      if (relu)   v = fmaxf(v, 0.f);
      stC(&C[(size_t)r*N + c], v);
    }
  }
}

// ---------------------------------------------------------------------------
// final-head GEMM (K=512, N=64, block-diag Wd) + fused per-row softmax -> out
// ---------------------------------------------------------------------------
__global__ __launch_bounds__(256) void gemm_fin(
    const bf16* __restrict__ A, const bf16* __restrict__ Bt,
    const float* __restrict__ bias, float* __restrict__ out)
{
  __shared__ __align__(16) bf16 Asl[64*72];
  __shared__ __align__(16) bf16 Bsl[64*72];
  const int K = 512;
  int tid = threadIdx.x;
  int w = tid >> 6, lane = tid & 63;
  int q = lane >> 4, mn = lane & 15;
  int row0 = blockIdx.x*64;
  int sr = tid >> 3, sc = tid & 7;
  floatx4 acc[4];
  #pragma unroll
  for (int t = 0; t < 4; t++) acc[t] = (floatx4){0.f, 0.f, 0.f, 0.f};
  for (int k0 = 0; k0 < K; k0 += 64) {
    uint4 a0 = *(const uint4*)(A  + (size_t)(row0 + sr)*K      + k0 + sc*8);
    uint4 a1 = *(const uint4*)(A  + (size_t)(row0 + 32 + sr)*K + k0 + sc*8);
    uint4 b0 = *(const uint4*)(Bt + (size_t)sr*K      + k0 + sc*8);
    uint4 b1 = *(const uint4*)(Bt + (size_t)(32 + sr)*K + k0 + sc*8);
    __syncthreads();
    *(uint4*)&Asl[sr*72 + sc*8]        = a0;
    *(uint4*)&Asl[(sr + 32)*72 + sc*8] = a1;
    *(uint4*)&Bsl[sr*72 + sc*8]        = b0;
    *(uint4*)&Bsl[(sr + 32)*72 + sc*8] = b1;
    __syncthreads();
    #pragma unroll
    for (int kk = 0; kk < 64; kk += 32) {
      short8 af = *(const short8*)&Asl[(w*16 + mn)*72 + kk + q*8];
      #pragma unroll
      for (int t = 0; t < 4; t++) {
        short8 bfr = *(const short8*)&Bsl[(t*16 + mn)*72 + kk + q*8];
        acc[t] = __builtin_amdgcn_mfma_f32_16x16x32_bf16(af, bfr, acc[t], 0, 0, 0);
      }
    }
  }
  #pragma unroll
  for (int rg = 0; rg < 4; rg++) {
    int r = row0 + w*16 + q*4 + rg;
    float mx = -1e30f;
    #pragma unroll
    for (int t = 0; t < 4; t++) {
      int c = t*16 + mn;
      float val = acc[t][rg] + bias[c];
      if (c >= 3 && c < 23) mx = fmaxf(mx, val);
    }
    #pragma unroll
    for (int off = 1; off < 16; off <<= 1) mx = fmaxf(mx, __shfl_xor(mx, off));
    float sum = 0.f;
    #pragma unroll
    for (int t = 0; t < 4; t++) {
      int c = t*16 + mn;
      float val = acc[t][rg] + bias[c];
      if (c >= 3 && c < 23) sum += expf(val - mx);
    }
    #pragma unroll
    for (int off = 1; off < 16; off <<= 1) sum += __shfl_xor(sum, off);
    float inv = 1.f / sum;
    #pragma unroll
    for (int t = 0; t < 2; t++) {
      int c = t*16 + mn;
      float val = acc[t][rg] + bias[c];
      if (c < 3) out[(size_t)r*3 + c] = val;
      else if (c < 23) out[24576 + (size_t)r*20 + (c - 3)] = expf(val - mx)*inv;
    }
  }
}

// ---------------------------------------------------------------------------
// GAT aggregation v2 (round-7 measured-fastest): block per dst node, wave per
// head; LDS-cached edge list + softmax weights; lane covers 4 channels (8B
// loads). Epilogue: head-mean+bias+relu, +edit (L1) or fused comb (L2).
// (v3 half-wave/16B variant was neutral-to-worse in round 9 — reverted.)
// ---------------------------------------------------------------------------
__global__ __launch_bounds__(256) void gat_aggregate(
    const bf16* __restrict__ xw, const float* __restrict__ a_s, const float* __restrict__ a_d,
    const int* __restrict__ offs, const int* __restrict__ csr,
    const float* __restrict__ bias, const float* __restrict__ editadd,
    const float* __restrict__ ctext, const float* __restrict__ cedit,
    const float* __restrict__ cmha,
    bf16* __restrict__ xout)
{
  int i = blockIdx.x, t = threadIdx.x;
  int h = t >> 6, l = t & 63;
  int beg = offs[i], end = offs[i + 1], deg = end - beg;
  __shared__ float sacc[HD];
  __shared__ float sal[4][DEGCAP];
  __shared__ int   scsr[DEGCAP];
  float adh = a_d[i*4 + h];
  float mloc = -1e30f;
  for (int idx = l; idx < deg; idx += 64) {
    int sn = csr[beg + idx];
    if (h == 0 && idx < DEGCAP) scsr[idx] = sn;
    float al = a_s[sn*4 + h] + adh;
    al = al > 0.f ? al : 0.2f*al;
    if (idx < DEGCAP) sal[h][idx] = al;
    mloc = fmaxf(mloc, al);
  }
  float mh = wredmax(mloc);                     // finite: deg >= 1
  float sloc = 0.f;
  for (int idx = l; idx < deg; idx += 64) {
    float al;
    if (idx < DEGCAP) al = sal[h][idx];
    else {
      int sn = csr[beg + idx];
      al = a_s[sn*4 + h] + adh;
      al = al > 0.f ? al : 0.2f*al;
    }
    float wv = expf(al - mh);
    if (idx < DEGCAP) sal[h][idx] = wv;
    sloc += wv;
  }
  float inv = 1.f / wredsum(sloc);              // denom >= 1
  __syncthreads();
  const bf16* xbase = xw + h*DD + l*4;
  float acc0 = 0.f, acc1 = 0.f, acc2 = 0.f, acc3 = 0.f;
  int cached = deg < DEGCAP ? deg : DEGCAP;
  for (int idx = 0; idx < cached; idx++) {
    int sn = scsr[idx];
    float wv = sal[h][idx];
    uint2 u = *(const uint2*)(xbase + (size_t)sn*HD);
    acc0 += wv*bf_lo(u.x); acc1 += wv*bf_hi(u.x);
    acc2 += wv*bf_lo(u.y); acc3 += wv*bf_hi(u.y);
  }
  for (int idx = cached; idx < deg; idx++) {    // cold path (deg > DEGCAP)
    int sn = csr[beg + idx];
    float al = a_s[sn*4 + h] + adh;
    al = al > 0.f ? al : 0.2f*al;
    float wv = expf(al - mh);
    uint2 u = *(const uint2*)(xbase + (size_t)sn*HD);
    acc0 += wv*bf_lo(u.x); acc1 += wv*bf_hi(u.x);
    acc2 += wv*bf_lo(u.y); acc3 += wv*bf_hi(u.y);
  }
  sacc[h*DD + l*4 + 0] = acc0*inv;
  sacc[h*DD + l*4 + 1] = acc1*inv;
  sacc[h*DD + l*4 + 2] = acc2*inv;
  sacc[h*DD + l*4 + 3] = acc3*inv;
  __syncthreads();
  if (t < 64) {                                  // wave 0 only
    int b = i >> 10;
    float v[4], tx[4], ex[4];
    #pragma unroll
    for (int j = 0; j < 4; j++) {
      int d = t*4 + j;
      float x = 0.25f*(sacc[d] + sacc[DD + d] + sacc[2*DD + d] + sacc[3*DD + d]) + bias[d];
      v[j] = fmaxf(x, 0.f);                      // relu from reference
    }
    if (cmha) {
      // fused comb: node + softmax2(node.textf, node.editp)@[textf;editp] + mhavec
      float s0 = 0.f, s1 = 0.f;
      #pragma unroll
      for (int j = 0; j < 4; j++) {
        int d = t*4 + j;
        tx[j] = ctext[b*DD + d]; ex[j] = cedit[b*DD + d];
        s0 += v[j]*tx[j]; s1 += v[j]*ex[j];
      }
      s0 = wredsum(s0); s1 = wredsum(s1);
      float mm = fmaxf(s0, s1);
      float e0 = expf(s0 - mm), e1 = expf(s1 - mm);
      float inv2 = 1.f / (e0 + e1);
      float p0 = e0*inv2, p1 = e1*inv2;
      #pragma unroll
      for (int j = 0; j < 4; j++) {
        int d = t*4 + j;
        xout[(size_t)i*DD + d] = __float2bfloat16(v[j] + p0*tx[j] + p1*ex[j] + cmha[b*DD + d]);
      }
    } else {
      #pragma unroll
      for (int j = 0; j < 4; j++) {
        int d = t*4 + j;
        float x = v[j];
        if (editadd) x += editadd[b*DD + d];     // + edit_flat for next layer input
        xout[(size_t)i*DD + d] = __float2bfloat16(x);
      }
    }
  }
}

// ---------------------------------------------------------------------------
extern "C" void kernel_launch(void* const* d_in, const int* in_sizes, int n_in,
                              void* d_out, int out_size, void* d_ws, size_t ws_size,
                              hipStream_t stream)
{
  (void)in_sizes; (void)n_in; (void)out_size; (void)ws_size;
  const float* structure_emb = (const float*)d_in[0];
  const float* text_emb      = (const float*)d_in[1];
  const float* edit_emb      = (const float*)d_in[3];
  const float* ws_w    = (const float*)d_in[4];
  const float* bs_b    = (const float*)d_in[5];
  const float* wt_w    = (const float*)d_in[6];
  const float* bt_b    = (const float*)d_in[7];
  const float* we_w    = (const float*)d_in[8];
  const float* be_b    = (const float*)d_in[9];
  const float* wp_w    = (const float*)d_in[10];
  const float* bp_b    = (const float*)d_in[11];
  const float* g1_lin  = (const float*)d_in[12];
  const float* g1_as   = (const float*)d_in[13];
  const float* g1_ad   = (const float*)d_in[14];
  const float* g1_b    = (const float*)d_in[15];
  const float* g2_lin  = (const float*)d_in[16];
  const float* g2_as   = (const float*)d_in[17];
  const float* g2_ad   = (const float*)d_in[18];
  const float* g2_b    = (const float*)d_in[19];
  const float* mha_iw  = (const float*)d_in[20];
  const float* mha_ib  = (const float*)d_in[21];
  const float* mha_ow  = (const float*)d_in[22];
  const float* mha_ob  = (const float*)d_in[23];
  const float* cw1     = (const float*)d_in[24];
  const float* cb1     = (const float*)d_in[25];
  const float* cw2     = (const float*)d_in[26];
  const float* cb2     = (const float*)d_in[27];
  const float* aw1     = (const float*)d_in[28];
  const float* ab1     = (const float*)d_in[29];
  const float* aw2     = (const float*)d_in[30];
  const float* ab2     = (const float*)d_in[31];
  const int*  edge_index = (const int*)d_in[32];
  float* out = (float*)d_out;

  // --- workspace layout (~22 MB) ---
  char* p = (char*)d_ws;
  // 16 MB big region, time-multiplexed: xwb (16MB) -> h1b (8MB)
  bf16*  xwb   = (bf16*)p;
  bf16*  h1b   = (bf16*)p;
  p += 16777216;
  bf16* bufB = (bf16*)p; p += 4194304;   // [8192][256] bf16: x0 -> x1e -> node2+comb
  bf16* g1T  = (bf16*)p; p += 524288;    // [1024][256]
  bf16* g2T  = (bf16*)p; p += 524288;
  bf16* W2T  = (bf16*)p; p += 262144;    // [512][256]: cw1T ++ aw1T
  bf16* WfT  = (bf16*)p; p += 393216;    // [256][768]
  bf16* WdT  = (bf16*)p; p += 65536;     // [64][512] block-diag final weight
  float* textf  = (float*)p; p += 8192;
  float* editp  = (float*)p; p += 8192;
  float* vhws   = (float*)p; p += 8192;
  float* mhavec = (float*)p; p += 8192;
  float* cvec   = (float*)p; p += 8192;
  float* bias2  = (float*)p; p += 2048;
  float* bias23 = (float*)p; p += 256;
  float* a_s1   = (float*)p; p += 131072;  // zz block: a_s1,a_d1,a_s2,a_d2
  float* a_d1   = (float*)p; p += 131072;
  float* a_s2   = (float*)p; p += 131072;
  float* a_d2   = (float*)p; p += 131072;
  int* counts = (int*)p; p += 32768;
  int* offs   = (int*)p; p += 32784;
  int* fc     = (int*)p; p += 32768;
  int* csr    = (int*)p; p += NEP*4;

  // 3 consolidated prep launches + csr_fill
  prep1<<<928, 256, 0, stream>>>(
      text_emb, edit_emb, wt_w, bt_b, we_w, be_b, textf, editp,
      ws_w, wp_w, WfT,
      g1_lin, g1T, g2_lin, g2T, cw1, aw1, W2T,
      cw2, cb2, aw2, ab2, WdT, bias23,
      counts, fc, a_s1, cb1, ab1, bias2);
  prep2<<<1056, 256, 0, stream>>>(
      textf, editp, mha_iw, mha_ib, vhws, bs_b, wp_w, bp_b, cvec,
      edge_index, counts);
  prep3<<<129, 1024, 0, stream>>>(vhws, mha_ow, mha_ob, mhavec, counts, offs);
  csr_fill<<<(NEP + 255)/256, 256, 0, stream>>>(edge_index, offs, fc, csr);

  // x0 = structure_emb(fp32, converted in-staging) @ Wfull + cvec[batch] -> bufB
  gemm_mfma<float, bf16><<<dim3(DD/64, BN/64), 256, 0, stream>>>(
      structure_emb, WfT, bufB, BN, DD, DSS, nullptr, cvec, 0,
      nullptr, nullptr, nullptr, nullptr);

  // GAT layer 1 (xw gemm + fused attention scores)
  gemm_mfma<bf16, bf16><<<dim3(HD/64, BN/64), 256, 0, stream>>>(
      bufB, g1T, xwb, BN, HD, DD, nullptr, nullptr, 0,
      g1_as, g1_ad, a_s1, a_d1);
  gat_aggregate<<<BN, 256, 0, stream>>>(xwb, a_s1, a_d1, offs, csr, g1_b, editp,
                                        nullptr, nullptr, nullptr, bufB);

  // GAT layer 2 (+ fused comb epilogue)
  gemm_mfma<bf16, bf16><<<dim3(HD/64, BN/64), 256, 0, stream>>>(
      bufB, g2T, xwb, BN, HD, DD, nullptr, nullptr, 0,
      g2_as, g2_ad, a_s2, a_d2);
  gat_aggregate<<<BN, 256, 0, stream>>>(xwb, a_s2, a_d2, offs, csr, g2_b, nullptr,
                                        textf, editp, mhavec, bufB);

  // combined head gemm -> h1b bf16 [8192][512]
  gemm_mfma<bf16, bf16><<<dim3(512/64, BN/64), 256, 0, stream>>>(
      bufB, W2T, h1b, BN, 512, DD, bias2, nullptr, 1,
      nullptr, nullptr, nullptr, nullptr);

  // final projection + fused softmax -> d_out
  gemm_fin<<<BN/64, 256, 0, stream>>>(h1b, WdT, bias23, out);
}

// Round 11
// 343.702 us; speedup vs baseline: 1.0213x; 1.0213x over previous
//
#include <hip/hip_runtime.h>
#include <hip/hip_bf16.h>

// Problem constants
#define BB 8
#define NN 1024
#define BN 8192       // B*N
#define DD 256
#define HEADS 4
#define HD 1024       // HEADS*D
#define DSS 768
#define DTT 128
#define NE 131072     // raw edges
#define NEP (NE + BN) // + self loops
#define DEGCAP 256    // LDS-cached edges per node (max in-degree ~40 for this input)

typedef __hip_bfloat16 bf16;
typedef __attribute__((ext_vector_type(8))) short short8;   // 8 bf16 (4 VGPRs)
typedef __attribute__((ext_vector_type(4))) float floatx4;  // MFMA C/D

__device__ __forceinline__ float toF(bf16 x){ return __bfloat162float(x); }
__device__ __forceinline__ void stC(float* p, float v){ *p = v; }
__device__ __forceinline__ void stC(bf16* p, float v){ *p = __float2bfloat16(v); }
__device__ __forceinline__ float bf_lo(unsigned u){ return __uint_as_float(u << 16); }
__device__ __forceinline__ float bf_hi(unsigned u){ return __uint_as_float(u & 0xffff0000u); }

__device__ __forceinline__ float wredsum(float v){
  #pragma unroll
  for (int off = 32; off; off >>= 1) v += __shfl_xor(v, off);
  return v;
}
__device__ __forceinline__ float wredmax(float v){
  #pragma unroll
  for (int off = 32; off; off >>= 1) v = fmaxf(v, __shfl_xor(v, off));
  return v;
}

// transpose one 32x32 tile: dst[c][r] = bf16(src[r][c]) (whole block same branch)
__device__ __forceinline__ void dev_transpose(
    float tb[32][33], const float* __restrict__ src, bf16* __restrict__ dst,
    int R, int C, int bx, int by, int tid)
{
  int c0 = bx*32, r0 = by*32;
  int tr = tid >> 5, tc = tid & 31;
  #pragma unroll
  for (int i = 0; i < 4; i++)
    tb[tr + i*8][tc] = src[(size_t)(r0 + tr + i*8)*C + c0 + tc];
  __syncthreads();
  #pragma unroll
  for (int i = 0; i < 4; i++)
    dst[(size_t)(c0 + tr + i*8)*R + r0 + tc] = __float2bfloat16(tb[tc][tr + i*8]);
}

// ---------------------------------------------------------------------------
// prep1: ALL independent prep work in one launch, partitioned by block range.
//  [0,32)      textf/editp projections
//  [32,128)    WfullT (ws@wp fused weight, transposed bf16)
//  [128,6272)  structure_emb fp32->bf16   (separate from GEMM: fused variant
//              read 100MB vs 87MB and regressed — round 10)
//  [6272,6528) g1_lin transpose -> g1T
//  [6528,6784) g2_lin transpose -> g2T
//  [6784,6848) cw1 transpose -> W2T[0:256]
//  [6848,6912) aw1 transpose -> W2T[256:512]
//  [6912,7040) WdT block-diag final weight + bias23
//  [7040,7072) CSR init + zero a_s/a_d accumulators + bias2 concat
// ---------------------------------------------------------------------------
__global__ __launch_bounds__(256) void prep1(
    const float* __restrict__ text_emb, const float* __restrict__ edit_emb,
    const float* __restrict__ wt, const float* __restrict__ bt,
    const float* __restrict__ we, const float* __restrict__ be,
    float* __restrict__ textf, float* __restrict__ editp,
    const float* __restrict__ wsm, const float* __restrict__ wp, bf16* __restrict__ WfT,
    const float* __restrict__ semb, bf16* __restrict__ sembB,
    const float* __restrict__ g1_lin, bf16* __restrict__ g1T,
    const float* __restrict__ g2_lin, bf16* __restrict__ g2T,
    const float* __restrict__ cw1, const float* __restrict__ aw1, bf16* __restrict__ W2T,
    const float* __restrict__ cw2, const float* __restrict__ cb2,
    const float* __restrict__ aw2, const float* __restrict__ ab2,
    bf16* __restrict__ WdT, float* __restrict__ bias23,
    int* __restrict__ counts, int* __restrict__ fc, float* __restrict__ zz,
    const float* __restrict__ cb1, const float* __restrict__ ab1, float* __restrict__ bias2)
{
  __shared__ float tpose[32][33];
  __shared__ float red[2][4][64];
  int blk = blockIdx.x, tid = threadIdx.x;
  if (blk < 32) {
    int b = blk & 7, l = tid & 63, qq = tid >> 6;
    int d = (blk >> 3)*64 + l;
    float tf = 0.f;
    for (int k = qq*32; k < qq*32 + 32; k++) tf += text_emb[b*DTT + k] * wt[(size_t)k*DD + d];
    float ep = 0.f;
    for (int k = qq*192; k < qq*192 + 192; k++) ep += edit_emb[b*DSS + k] * we[(size_t)k*DD + d];
    red[0][qq][l] = tf; red[1][qq][l] = ep;
    __syncthreads();
    if (tid < 64) {
      int dd = (blk >> 3)*64 + tid;
      textf[b*DD + dd] = red[0][0][tid]+red[0][1][tid]+red[0][2][tid]+red[0][3][tid] + bt[dd];
      editp[b*DD + dd] = red[1][0][tid]+red[1][1][tid]+red[1][2][tid]+red[1][3][tid] + be[dd];
    }
  } else if (blk < 128) {
    int k0 = (blk - 32)*8, d = tid;
    float acc[8] = {};
    for (int j = 0; j < DD; j++) {
      float wv = wp[(size_t)j*DD + d];
      #pragma unroll
      for (int kk = 0; kk < 8; kk++) acc[kk] += wsm[(size_t)(k0 + kk)*DD + j] * wv;
    }
    #pragma unroll
    for (int kk = 0; kk < 8; kk++) WfT[(size_t)d*DSS + k0 + kk] = __float2bfloat16(acc[kk]);
  } else if (blk < 6272) {
    int i = ((blk - 128)*256 + tid)*4;
    float4 v = *(const float4*)(semb + i);
    bf16 t4[4] = {__float2bfloat16(v.x), __float2bfloat16(v.y),
                  __float2bfloat16(v.z), __float2bfloat16(v.w)};
    *(uint2*)(sembB + i) = *(uint2*)t4;
  } else if (blk < 6528) {
    int lo = blk - 6272; dev_transpose(tpose, g1_lin, g1T, DD, HD, lo & 31, lo >> 5, tid);
  } else if (blk < 6784) {
    int lo = blk - 6528; dev_transpose(tpose, g2_lin, g2T, DD, HD, lo & 31, lo >> 5, tid);
  } else if (blk < 6848) {
    int lo = blk - 6784; dev_transpose(tpose, cw1, W2T, DD, DD, lo & 7, lo >> 3, tid);
  } else if (blk < 6912) {
    int lo = blk - 6848; dev_transpose(tpose, aw1, W2T + 65536, DD, DD, lo & 7, lo >> 3, tid);
  } else if (blk < 7040) {
    int idx = (blk - 6912)*256 + tid;     // 0..32767
    int n = idx >> 9, k = idx & 511;
    float v = 0.f;
    if (n < 3) { if (k < 256) v = cw2[(size_t)k*3 + n]; }
    else if (n < 23) { if (k >= 256) v = aw2[(size_t)(k - 256)*20 + (n - 3)]; }
    WdT[idx] = __float2bfloat16(v);
    if (idx < 64) bias23[idx] = idx < 3 ? cb2[idx] : (idx < 23 ? ab2[idx - 3] : 0.f);
  } else {
    int i = (blk - 7040)*256 + tid;       // 0..8191
    counts[i] = 1; fc[i] = 0;
    float4 z = make_float4(0.f, 0.f, 0.f, 0.f);
    #pragma unroll
    for (int j = 0; j < 4; j++) ((float4*)zz)[i*4 + j] = z;
    if (i < 256) bias2[i] = cb1[i];
    else if (i < 512) bias2[i] = ab1[i - 256];
  }
}

// ---------------------------------------------------------------------------
// prep2: vh + cvec + edge counting;  prep3: mhavec + CSR scan
// ---------------------------------------------------------------------------
__global__ __launch_bounds__(256) void prep2(
    const float* __restrict__ textf, const float* __restrict__ editp,
    const float* __restrict__ mha_iw, const float* __restrict__ mha_ib, float* __restrict__ vh,
    const float* __restrict__ bs, const float* __restrict__ wp, const float* __restrict__ bp,
    float* __restrict__ cvec,
    const int* __restrict__ ei, int* __restrict__ counts)
{
  __shared__ float red[4][64];
  int blk = blockIdx.x, tid = threadIdx.x;
  if (blk < 512) {
    int b = blk & 7, w = tid >> 6, l = tid & 63;
    int d = (blk >> 3)*4 + w;
    float p = 0.f;
    #pragma unroll
    for (int i = 0; i < 4; i++) p += textf[b*DD + l + 64*i] * mha_iw[(size_t)(512 + d)*DD + l + 64*i];
    p = wredsum(p);
    if (l == 0) vh[b*DD + d] = p + mha_ib[512 + d];
  } else if (blk < 544) {
    int lo = blk - 512;
    int b = lo & 7, l = tid & 63, qq = tid >> 6;
    int d = (lo >> 3)*64 + l;
    float cv = 0.f;
    for (int k = qq*64; k < qq*64 + 64; k++) cv += bs[k] * wp[(size_t)k*DD + d];
    for (int k = qq*64; k < qq*64 + 64; k++) cv += textf[b*DD + k] * wp[(size_t)(DD + k)*DD + d];
    for (int k = qq*64; k < qq*64 + 64; k++) cv += editp[b*DD + k] * wp[(size_t)(2*DD + k)*DD + d];
    red[qq][l] = cv;
    __syncthreads();
    if (tid < 64) {
      int dd = (lo >> 3)*64 + tid;
      cvec[b*DD + dd] = red[0][tid]+red[1][tid]+red[2][tid]+red[3][tid] + bp[dd] + editp[b*DD + dd];
    }
  } else {
    int e = (blk - 544)*256 + tid;
    if (e < NE) atomicAdd(&counts[ei[NE + e]], 1);
  }
}

__global__ __launch_bounds__(1024) void prep3(
    const float* __restrict__ vh, const float* __restrict__ mha_ow,
    const float* __restrict__ mha_ob, float* __restrict__ mhavec,
    const int* __restrict__ counts, int* __restrict__ offs)
{
  __shared__ int part[1024];
  int blk = blockIdx.x, t = threadIdx.x;
  if (blk < 128) {
    int b = blk >> 4, w16 = t >> 6, l = t & 63;
    int d = (blk & 15)*16 + w16;
    float p = 0.f;
    #pragma unroll
    for (int i = 0; i < 4; i++) p += vh[b*DD + l + 64*i] * mha_ow[(size_t)d*DD + l + 64*i];
    p = wredsum(p);
    if (l == 0) mhavec[b*DD + d] = p + mha_ob[d];
  } else {
    int local[8]; int sum = 0;
    #pragma unroll
    for (int i = 0; i < 8; i++) { local[i] = sum; sum += counts[t*8 + i]; }
    part[t] = sum;
    __syncthreads();
    for (int off = 1; off < 1024; off <<= 1) {
      int v = (t >= off) ? part[t - off] : 0;
      __syncthreads();
      part[t] += v;
      __syncthreads();
    }
    int base = (t == 0) ? 0 : part[t - 1];
    #pragma unroll
    for (int i = 0; i < 8; i++) offs[t*8 + i] = base + local[i];
    if (t == 1023) offs[BN] = part[1023];
  }
}

__global__ void csr_fill(const int* __restrict__ ei, const int* __restrict__ offs,
                         int* __restrict__ fc, int* __restrict__ csr)
{
  int idx = blockIdx.x*256 + threadIdx.x;
  if (idx < NE) {
    int sn = ei[idx], dn = ei[NE + idx];
    int p = offs[dn] + atomicAdd(&fc[dn], 1);
    csr[p] = sn;
  } else if (idx < NEP) {
    int i2 = idx - NE;
    int p = offs[i2] + atomicAdd(&fc[i2], 1);
    csr[p] = i2;
  }
}

// ---------------------------------------------------------------------------
// MFMA GEMM: C[M,N] = A[M,K] @ Bt[N,K]^T, bf16 in, fp32 acc, 64x64 tile.
// (128-tile regressed 3x in round 8: VGPR spill — WRITE_SIZE 75MB vs 16MB.)
// Optional fused epilogues: bias/rowvec/relu; GAT attention-score partials.
// ---------------------------------------------------------------------------
template<typename TC>
__global__ __launch_bounds__(256) void gemm_mfma(
    const bf16* __restrict__ A, const bf16* __restrict__ Bt, TC* __restrict__ C,
    int M, int N, int K,
    const float* __restrict__ bias, const float* __restrict__ rowvec, int relu,
    const float* __restrict__ atts, const float* __restrict__ attd,
    float* __restrict__ as_out, float* __restrict__ ad_out)
{
  __shared__ __align__(16) bf16 Asl[64*72];
  __shared__ __align__(16) bf16 Bsl[64*72];
  int tid = threadIdx.x;
  int w = tid >> 6, lane = tid & 63;
  int q = lane >> 4, mn = lane & 15;
  int row0 = blockIdx.y*64, col0 = blockIdx.x*64;
  int sr = tid >> 3, sc = tid & 7;
  floatx4 acc[4];
  #pragma unroll
  for (int t = 0; t < 4; t++) acc[t] = (floatx4){0.f, 0.f, 0.f, 0.f};

  for (int k0 = 0; k0 < K; k0 += 64) {
    uint4 a0 = *(const uint4*)(A  + (size_t)(row0 + sr)*K      + k0 + sc*8);
    uint4 a1 = *(const uint4*)(A  + (size_t)(row0 + 32 + sr)*K + k0 + sc*8);
    uint4 b0 = *(const uint4*)(Bt + (size_t)(col0 + sr)*K      + k0 + sc*8);
    uint4 b1 = *(const uint4*)(Bt + (size_t)(col0 + 32 + sr)*K + k0 + sc*8);
    __syncthreads();
    *(uint4*)&Asl[sr*72 + sc*8]        = a0;
    *(uint4*)&Asl[(sr + 32)*72 + sc*8] = a1;
    *(uint4*)&Bsl[sr*72 + sc*8]        = b0;
    *(uint4*)&Bsl[(sr + 32)*72 + sc*8] = b1;
    __syncthreads();
    #pragma unroll
    for (int kk = 0; kk < 64; kk += 32) {
      short8 af = *(const short8*)&Asl[(w*16 + mn)*72 + kk + q*8];
      #pragma unroll
      for (int t = 0; t < 4; t++) {
        short8 bfr = *(const short8*)&Bsl[(t*16 + mn)*72 + kk + q*8];
        acc[t] = __builtin_amdgcn_mfma_f32_16x16x32_bf16(af, bfr, acc[t], 0, 0, 0);
      }
    }
  }
  if (as_out) {   // fused GAT attention-score partials (head h = col0>>8)
    int h = col0 >> 8, cbase = col0 & 255;
    float ps[4] = {}, pd[4] = {};
    #pragma unroll
    for (int t = 0; t < 4; t++) {
      float av = atts[h*DD + cbase + t*16 + mn];
      float dv = attd[h*DD + cbase + t*16 + mn];
      #pragma unroll
      for (int rg = 0; rg < 4; rg++) {
        ps[rg] += acc[t][rg]*av;
        pd[rg] += acc[t][rg]*dv;
      }
    }
    #pragma unroll
    for (int rg = 0; rg < 4; rg++) {
      #pragma unroll
      for (int off = 1; off < 16; off <<= 1) {
        ps[rg] += __shfl_xor(ps[rg], off);
        pd[rg] += __shfl_xor(pd[rg], off);
      }
      if (mn == 0) {
        int r = row0 + w*16 + q*4 + rg;
        atomicAdd(&as_out[r*4 + h], ps[rg]);
        atomicAdd(&ad_out[r*4 + h], pd[rg]);
      }
    }
  }
  #pragma unroll
  for (int t = 0; t < 4; t++) {
    #pragma unroll
    for (int rg = 0; rg < 4; rg++) {
      int r = row0 + w*16 + q*4 + rg;
      int c = col0 + t*16 + mn;
      float v = acc[t][rg];
      if (bias)   v += bias[c];
      if (rowvec) v += rowvec[(size_t)(r >> 10)*N + c];
      if (relu)   v = fmaxf(v, 0.f);
      stC(&C[(size_t)r*N + c], v);
    }
  }
}

// ---------------------------------------------------------------------------
// final-head GEMM (K=512, N=64, block-diag Wd) + fused per-row softmax -> out
// ---------------------------------------------------------------------------
__global__ __launch_bounds__(256) void gemm_fin(
    const bf16* __restrict__ A, const bf16* __restrict__ Bt,
    const float* __restrict__ bias, float* __restrict__ out)
{
  __shared__ __align__(16) bf16 Asl[64*72];
  __shared__ __align__(16) bf16 Bsl[64*72];
  const int K = 512;
  int tid = threadIdx.x;
  int w = tid >> 6, lane = tid & 63;
  int q = lane >> 4, mn = lane & 15;
  int row0 = blockIdx.x*64;
  int sr = tid >> 3, sc = tid & 7;
  floatx4 acc[4];
  #pragma unroll
  for (int t = 0; t < 4; t++) acc[t] = (floatx4){0.f, 0.f, 0.f, 0.f};
  for (int k0 = 0; k0 < K; k0 += 64) {
    uint4 a0 = *(const uint4*)(A  + (size_t)(row0 + sr)*K      + k0 + sc*8);
    uint4 a1 = *(const uint4*)(A  + (size_t)(row0 + 32 + sr)*K + k0 + sc*8);
    uint4 b0 = *(const uint4*)(Bt + (size_t)sr*K      + k0 + sc*8);
    uint4 b1 = *(const uint4*)(Bt + (size_t)(32 + sr)*K + k0 + sc*8);
    __syncthreads();
    *(uint4*)&Asl[sr*72 + sc*8]        = a0;
    *(uint4*)&Asl[(sr + 32)*72 + sc*8] = a1;
    *(uint4*)&Bsl[sr*72 + sc*8]        = b0;
    *(uint4*)&Bsl[(sr + 32)*72 + sc*8] = b1;
    __syncthreads();
    #pragma unroll
    for (int kk = 0; kk < 64; kk += 32) {
      short8 af = *(const short8*)&Asl[(w*16 + mn)*72 + kk + q*8];
      #pragma unroll
      for (int t = 0; t < 4; t++) {
        short8 bfr = *(const short8*)&Bsl[(t*16 + mn)*72 + kk + q*8];
        acc[t] = __builtin_amdgcn_mfma_f32_16x16x32_bf16(af, bfr, acc[t], 0, 0, 0);
      }
    }
  }
  #pragma unroll
  for (int rg = 0; rg < 4; rg++) {
    int r = row0 + w*16 + q*4 + rg;
    float mx = -1e30f;
    #pragma unroll
    for (int t = 0; t < 4; t++) {
      int c = t*16 + mn;
      float val = acc[t][rg] + bias[c];
      if (c >= 3 && c < 23) mx = fmaxf(mx, val);
    }
    #pragma unroll
    for (int off = 1; off < 16; off <<= 1) mx = fmaxf(mx, __shfl_xor(mx, off));
    float sum = 0.f;
    #pragma unroll
    for (int t = 0; t < 4; t++) {
      int c = t*16 + mn;
      float val = acc[t][rg] + bias[c];
      if (c >= 3 && c < 23) sum += expf(val - mx);
    }
    #pragma unroll
    for (int off = 1; off < 16; off <<= 1) sum += __shfl_xor(sum, off);
    float inv = 1.f / sum;
    #pragma unroll
    for (int t = 0; t < 2; t++) {
      int c = t*16 + mn;
      float val = acc[t][rg] + bias[c];
      if (c < 3) out[(size_t)r*3 + c] = val;
      else if (c < 23) out[24576 + (size_t)r*20 + (c - 3)] = expf(val - mx)*inv;
    }
  }
}

// ---------------------------------------------------------------------------
// GAT aggregation v2 (measured-fastest): block per dst node, wave per head;
// LDS-cached edge list + softmax weights; lane covers 4 channels (8B loads).
// Epilogue: head-mean+bias+relu, +edit (L1) or fused comb (L2). bf16 out.
// (v3 half-wave/16B variant regressed in round 9; gather is LLC-BW-bound.)
// ---------------------------------------------------------------------------
__global__ __launch_bounds__(256) void gat_aggregate(
    const bf16* __restrict__ xw, const float* __restrict__ a_s, const float* __restrict__ a_d,
    const int* __restrict__ offs, const int* __restrict__ csr,
    const float* __restrict__ bias, const float* __restrict__ editadd,
    const float* __restrict__ ctext, const float* __restrict__ cedit,
    const float* __restrict__ cmha,
    bf16* __restrict__ xout)
{
  int i = blockIdx.x, t = threadIdx.x;
  int h = t >> 6, l = t & 63;
  int beg = offs[i], end = offs[i + 1], deg = end - beg;
  __shared__ float sacc[HD];
  __shared__ float sal[4][DEGCAP];
  __shared__ int   scsr[DEGCAP];
  float adh = a_d[i*4 + h];
  float mloc = -1e30f;
  for (int idx = l; idx < deg; idx += 64) {
    int sn = csr[beg + idx];
    if (h == 0 && idx < DEGCAP) scsr[idx] = sn;
    float al = a_s[sn*4 + h] + adh;
    al = al > 0.f ? al : 0.2f*al;
    if (idx < DEGCAP) sal[h][idx] = al;
    mloc = fmaxf(mloc, al);
  }
  float mh = wredmax(mloc);                     // finite: deg >= 1
  float sloc = 0.f;
  for (int idx = l; idx < deg; idx += 64) {
    float al;
    if (idx < DEGCAP) al = sal[h][idx];
    else {
      int sn = csr[beg + idx];
      al = a_s[sn*4 + h] + adh;
      al = al > 0.f ? al : 0.2f*al;
    }
    float wv = expf(al - mh);
    if (idx < DEGCAP) sal[h][idx] = wv;
    sloc += wv;
  }
  float inv = 1.f / wredsum(sloc);              // denom >= 1
  __syncthreads();
  const bf16* xbase = xw + h*DD + l*4;
  float acc0 = 0.f, acc1 = 0.f, acc2 = 0.f, acc3 = 0.f;
  int cached = deg < DEGCAP ? deg : DEGCAP;
  for (int idx = 0; idx < cached; idx++) {
    int sn = scsr[idx];
    float wv = sal[h][idx];
    uint2 u = *(const uint2*)(xbase + (size_t)sn*HD);
    acc0 += wv*bf_lo(u.x); acc1 += wv*bf_hi(u.x);
    acc2 += wv*bf_lo(u.y); acc3 += wv*bf_hi(u.y);
  }
  for (int idx = cached; idx < deg; idx++) {    // cold path (deg > DEGCAP)
    int sn = csr[beg + idx];
    float al = a_s[sn*4 + h] + adh;
    al = al > 0.f ? al : 0.2f*al;
    float wv = expf(al - mh);
    uint2 u = *(const uint2*)(xbase + (size_t)sn*HD);
    acc0 += wv*bf_lo(u.x); acc1 += wv*bf_hi(u.x);
    acc2 += wv*bf_lo(u.y); acc3 += wv*bf_hi(u.y);
  }
  sacc[h*DD + l*4 + 0] = acc0*inv;
  sacc[h*DD + l*4 + 1] = acc1*inv;
  sacc[h*DD + l*4 + 2] = acc2*inv;
  sacc[h*DD + l*4 + 3] = acc3*inv;
  __syncthreads();
  if (t < 64) {                                  // wave 0 only
    int b = i >> 10;
    float v[4], tx[4], ex[4];
    #pragma unroll
    for (int j = 0; j < 4; j++) {
      int d = t*4 + j;
      float x = 0.25f*(sacc[d] + sacc[DD + d] + sacc[2*DD + d] + sacc[3*DD + d]) + bias[d];
      v[j] = fmaxf(x, 0.f);                      // relu from reference
    }
    if (cmha) {
      // fused comb: node + softmax2(node.textf, node.editp)@[textf;editp] + mhavec
      float s0 = 0.f, s1 = 0.f;
      #pragma unroll
      for (int j = 0; j < 4; j++) {
        int d = t*4 + j;
        tx[j] = ctext[b*DD + d]; ex[j] = cedit[b*DD + d];
        s0 += v[j]*tx[j]; s1 += v[j]*ex[j];
      }
      s0 = wredsum(s0); s1 = wredsum(s1);
      float mm = fmaxf(s0, s1);
      float e0 = expf(s0 - mm), e1 = expf(s1 - mm);
      float inv2 = 1.f / (e0 + e1);
      float p0 = e0*inv2, p1 = e1*inv2;
      #pragma unroll
      for (int j = 0; j < 4; j++) {
        int d = t*4 + j;
        xout[(size_t)i*DD + d] = __float2bfloat16(v[j] + p0*tx[j] + p1*ex[j] + cmha[b*DD + d]);
      }
    } else {
      #pragma unroll
      for (int j = 0; j < 4; j++) {
        int d = t*4 + j;
        float x = v[j];
        if (editadd) x += editadd[b*DD + d];     // + edit_flat for next layer input
        xout[(size_t)i*DD + d] = __float2bfloat16(x);
      }
    }
  }
}

// ---------------------------------------------------------------------------
extern "C" void kernel_launch(void* const* d_in, const int* in_sizes, int n_in,
                              void* d_out, int out_size, void* d_ws, size_t ws_size,
                              hipStream_t stream)
{
  (void)in_sizes; (void)n_in; (void)out_size; (void)ws_size;
  const float* structure_emb = (const float*)d_in[0];
  const float* text_emb      = (const float*)d_in[1];
  const float* edit_emb      = (const float*)d_in[3];
  const float* ws_w    = (const float*)d_in[4];
  const float* bs_b    = (const float*)d_in[5];
  const float* wt_w    = (const float*)d_in[6];
  const float* bt_b    = (const float*)d_in[7];
  const float* we_w    = (const float*)d_in[8];
  const float* be_b    = (const float*)d_in[9];
  const float* wp_w    = (const float*)d_in[10];
  const float* bp_b    = (const float*)d_in[11];
  const float* g1_lin  = (const float*)d_in[12];
  const float* g1_as   = (const float*)d_in[13];
  const float* g1_ad   = (const float*)d_in[14];
  const float* g1_b    = (const float*)d_in[15];
  const float* g2_lin  = (const float*)d_in[16];
  const float* g2_as   = (const float*)d_in[17];
  const float* g2_ad   = (const float*)d_in[18];
  const float* g2_b    = (const float*)d_in[19];
  const float* mha_iw  = (const float*)d_in[20];
  const float* mha_ib  = (const float*)d_in[21];
  const float* mha_ow  = (const float*)d_in[22];
  const float* mha_ob  = (const float*)d_in[23];
  const float* cw1     = (const float*)d_in[24];
  const float* cb1     = (const float*)d_in[25];
  const float* cw2     = (const float*)d_in[26];
  const float* cb2     = (const float*)d_in[27];
  const float* aw1     = (const float*)d_in[28];
  const float* ab1     = (const float*)d_in[29];
  const float* aw2     = (const float*)d_in[30];
  const float* ab2     = (const float*)d_in[31];
  const int*  edge_index = (const int*)d_in[32];
  float* out = (float*)d_out;

  // --- workspace layout (~22 MB) ---
  char* p = (char*)d_ws;
  // 16 MB big region, time-multiplexed: sembB (12.6MB) -> xwb (16MB) -> h1b (8MB)
  bf16*  sembB = (bf16*)p;
  bf16*  xwb   = (bf16*)p;
  bf16*  h1b   = (bf16*)p;
  p += 16777216;
  bf16* bufB = (bf16*)p; p += 4194304;   // [8192][256] bf16: x0 -> x1e -> node2+comb
  bf16* g1T  = (bf16*)p; p += 524288;    // [1024][256]
  bf16* g2T  = (bf16*)p; p += 524288;
  bf16* W2T  = (bf16*)p; p += 262144;    // [512][256]: cw1T ++ aw1T
  bf16* WfT  = (bf16*)p; p += 393216;    // [256][768]
  bf16* WdT  = (bf16*)p; p += 65536;     // [64][512] block-diag final weight
  float* textf  = (float*)p; p += 8192;
  float* editp  = (float*)p; p += 8192;
  float* vhws   = (float*)p; p += 8192;
  float* mhavec = (float*)p; p += 8192;
  float* cvec   = (float*)p; p += 8192;
  float* bias2  = (float*)p; p += 2048;
  float* bias23 = (float*)p; p += 256;
  float* a_s1   = (float*)p; p += 131072;  // zz block: a_s1,a_d1,a_s2,a_d2
  float* a_d1   = (float*)p; p += 131072;
  float* a_s2   = (float*)p; p += 131072;
  float* a_d2   = (float*)p; p += 131072;
  int* counts = (int*)p; p += 32768;
  int* offs   = (int*)p; p += 32784;
  int* fc     = (int*)p; p += 32768;
  int* csr    = (int*)p; p += NEP*4;

  // 3 consolidated prep launches + csr_fill
  prep1<<<7072, 256, 0, stream>>>(
      text_emb, edit_emb, wt_w, bt_b, we_w, be_b, textf, editp,
      ws_w, wp_w, WfT, structure_emb, sembB,
      g1_lin, g1T, g2_lin, g2T, cw1, aw1, W2T,
      cw2, cb2, aw2, ab2, WdT, bias23,
      counts, fc, a_s1, cb1, ab1, bias2);
  prep2<<<1056, 256, 0, stream>>>(
      textf, editp, mha_iw, mha_ib, vhws, bs_b, wp_w, bp_b, cvec,
      edge_index, counts);
  prep3<<<129, 1024, 0, stream>>>(vhws, mha_ow, mha_ob, mhavec, counts, offs);
  csr_fill<<<(NEP + 255)/256, 256, 0, stream>>>(edge_index, offs, fc, csr);

  // x0 = semb @ Wfull + cvec[batch]  -> bufB (bf16)
  gemm_mfma<bf16><<<dim3(DD/64, BN/64), 256, 0, stream>>>(
      sembB, WfT, bufB, BN, DD, DSS, nullptr, cvec, 0,
      nullptr, nullptr, nullptr, nullptr);

  // GAT layer 1 (xw gemm + fused attention scores)
  gemm_mfma<bf16><<<dim3(HD/64, BN/64), 256, 0, stream>>>(
      bufB, g1T, xwb, BN, HD, DD, nullptr, nullptr, 0,
      g1_as, g1_ad, a_s1, a_d1);
  gat_aggregate<<<BN, 256, 0, stream>>>(xwb, a_s1, a_d1, offs, csr, g1_b, editp,
                                        nullptr, nullptr, nullptr, bufB);

  // GAT layer 2 (+ fused comb epilogue)
  gemm_mfma<bf16><<<dim3(HD/64, BN/64), 256, 0, stream>>>(
      bufB, g2T, xwb, BN, HD, DD, nullptr, nullptr, 0,
      g2_as, g2_ad, a_s2, a_d2);
  gat_aggregate<<<BN, 256, 0, stream>>>(xwb, a_s2, a_d2, offs, csr, g2_b, nullptr,
                                        textf, editp, mhavec, bufB);

  // combined head gemm -> h1b bf16 [8192][512] (xwb dead by now)
  gemm_mfma<bf16><<<dim3(512/64, BN/64), 256, 0, stream>>>(
      bufB, W2T, h1b, BN, 512, DD, bias2, nullptr, 1,
      nullptr, nullptr, nullptr, nullptr);

  // final projection + fused softmax -> d_out
  gemm_fin<<<BN/64, 256, 0, stream>>>(h1b, WdT, bias23, out);
}